// Round 1
// 309.353 us; speedup vs baseline: 1.0048x; 1.0048x over previous
//
#include <hip/hip_runtime.h>

#define B_  64
#define D_  4096
#define S_  128
#define N_  256
#define KC_ 4
#define KPB (D_ / KC_)     // 1024 K per kc slice
#define BK  64             // K per LDS chunk (was 32)
#define NCH (KPB / BK)     // 16 chunks
#define RS  72             // LDS row stride (shorts): 64 data + 8 pad, 144 B rows (16B-aligned)
#define LDSBUF (N_ * RS)   // 18432 shorts = 36 KB per buffer
#define TILE_ (N_ * N_)

using short8   = __attribute__((ext_vector_type(8)))  short;
using floatx16 = __attribute__((ext_vector_type(16))) float;

// hardware packed f32->bf16 (RNE), 1 instr per pair; non-volatile so the
// scheduler can interleave freely with vmcnt waits.
__device__ __forceinline__ unsigned int pk2(float lo, float hi) {
  unsigned int r;
  asm("v_cvt_pk_bf16_f32 %0, %1, %2" : "=v"(r) : "v"(lo), "v"(hi));
  return r;
}

// granule swizzle: row n base = n*36 dwords -> rows n, n+8, n+16, n+24 share a
// bank phase; XOR-ing granule low bits with (n&3)^((n>>3)&3) spreads them
// across distinct 16B slots. g in 0..7 (3 bits), XOR terms are 2-bit -> bijective.
__device__ __forceinline__ int swz(int n, int g) {
  return n * RS + ((g ^ (n & 3) ^ ((n >> 3) & 3)) << 3);
}

// partial[kc][b][rows][cols], each block computes a 128x256 row-half.
// Also accumulates tot[b] (full-tile sum) and sq[b][c] (diagonal).
__global__ __launch_bounds__(512, 4) void k_gram(
    const float* __restrict__ src, const float* __restrict__ tgt,
    float* __restrict__ partial, float* __restrict__ tot,
    float* __restrict__ sq) {
  __shared__ unsigned short lds[2 * LDSBUF];  // 72 KB -> 2 blocks/CU
  __shared__ float red[8];
  const int bx  = blockIdx.x;
  const int kc  = bx >> 1;
  const int rh  = bx & 1;              // row half
  const int b   = blockIdx.y;
  const int tid = threadIdx.x;
  const int l   = tid & 63;
  const int w   = tid >> 6;            // wave 0..7
  const int tr  = w >> 2;              // 0..1 (64-row group within half)
  const int tc  = w & 3;               // 0..3 (64-col group)

  // staging: thread owns column n_s; batch A = granules {g, g+2},
  // batch B = {g+4, g+6}; 16 floats (= 16 regs) live per batch.
  const int n_s = tid & 255;
  const int g   = tid >> 8;            // 0..1
  const float* colbase = (n_s < S_)
      ? (src + (size_t)b * D_ * S_ + n_s)
      : (tgt + (size_t)b * D_ * S_ + (n_s - S_));
  const float* pA = colbase + (size_t)kc * KPB * S_;

  float ld[16];
  floatx16 acc[2][2];
  #pragma unroll
  for (int i = 0; i < 2; i++)
    #pragma unroll
    for (int j = 0; j < 2; j++)
      #pragma unroll
      for (int r = 0; r < 16; r++) acc[i][j][r] = 0.f;

  const int lm   = l & 31;
  const int lk   = l >> 5;             // 0/1
  const int ar   = rh * 128 + tr * 64 + lm;  // A rows (sub adds 32)
  const int bcol = tc * 64 + lm;             // B cols (sub adds 32)

  #define LOADH(ch, gb)                                                \
    do {                                                               \
      const float* q = pA + (size_t)(ch) * BK * S_;                    \
      _Pragma("unroll")                                                \
      for (int j = 0; j < 8; j++) {                                    \
        ld[j]     = q[(size_t)(((gb)) * 8 + j) * S_];                  \
        ld[8 + j] = q[(size_t)(((gb) + 2) * 8 + j) * S_];              \
      }                                                                \
    } while (0)

  #define WRITEH(buf, gb)                                              \
    do {                                                               \
      uint4 wa, wb;                                                    \
      wa.x = pk2(ld[0],  ld[1]);                                       \
      wa.y = pk2(ld[2],  ld[3]);                                       \
      wa.z = pk2(ld[4],  ld[5]);                                       \
      wa.w = pk2(ld[6],  ld[7]);                                       \
      wb.x = pk2(ld[8],  ld[9]);                                       \
      wb.y = pk2(ld[10], ld[11]);                                      \
      wb.z = pk2(ld[12], ld[13]);                                      \
      wb.w = pk2(ld[14], ld[15]);                                      \
      const int base_ = (buf) * LDSBUF;                                \
      *(uint4*)&lds[base_ + swz(n_s, (gb))]     = wa;                  \
      *(uint4*)&lds[base_ + swz(n_s, (gb) + 2)] = wb;                  \
    } while (0)

  #define MFMA2(buf, k0)                                               \
    do {                                                               \
      const unsigned short* L = &lds[(buf) * LDSBUF];                  \
      _Pragma("unroll")                                                \
      for (int ks = (k0); ks < (k0) + 2; ks++) {                       \
        const int gg = ks * 2 + lk;                                    \
        short8 a0 = *(const short8*)&L[swz(ar,        gg)];            \
        short8 a1 = *(const short8*)&L[swz(ar + 32,   gg)];            \
        short8 b0 = *(const short8*)&L[swz(bcol,      gg)];            \
        short8 b1 = *(const short8*)&L[swz(bcol + 32, gg)];            \
        acc[0][0] = __builtin_amdgcn_mfma_f32_32x32x16_bf16(a0, b0, acc[0][0], 0, 0, 0); \
        acc[0][1] = __builtin_amdgcn_mfma_f32_32x32x16_bf16(a0, b1, acc[0][1], 0, 0, 0); \
        acc[1][0] = __builtin_amdgcn_mfma_f32_32x32x16_bf16(a1, b0, acc[1][0], 0, 0, 0); \
        acc[1][1] = __builtin_amdgcn_mfma_f32_32x32x16_bf16(a1, b1, acc[1][1], 0, 0, 0); \
      }                                                                \
    } while (0)

  // prologue: stage chunk 0 (both batches)
  LOADH(0, g);
  WRITEH(0, g);
  LOADH(0, g + 4);
  WRITEH(0, g + 4);
  __syncthreads();
  // steady state: each 16-load batch's vmcnt wait is covered by one MFMA pair;
  // barriers per K-tile halved vs BK=32 (16 total).
  for (int ch = 0; ch < NCH - 1; ch++) {
    LOADH(ch + 1, g);
    MFMA2(ch & 1, 0);
    WRITEH((ch + 1) & 1, g);
    LOADH(ch + 1, g + 4);
    MFMA2(ch & 1, 2);
    WRITEH((ch + 1) & 1, g + 4);
    __syncthreads();
  }
  MFMA2((NCH - 1) & 1, 0);
  MFMA2((NCH - 1) & 1, 2);

  // ---- epilogue: store partial half-tile (plain stores) ----
  float* gb = partial + ((size_t)kc * B_ + b) * TILE_;
  #pragma unroll
  for (int i = 0; i < 2; i++)
    #pragma unroll
    for (int j = 0; j < 2; j++)
      #pragma unroll
      for (int r = 0; r < 16; r++) {
        const int row = (r & 3) + 8 * (r >> 2) + 4 * lk;  // verified C/D layout
        const int nr  = rh * 128 + tr * 64 + i * 32 + row;
        const int nc  = tc * 64 + j * 32 + (l & 31);
        gb[nr * N_ + nc] = acc[i][j][r];
      }

  // ---- tot[b]: block-level sum of this partial half-tile ----
  float s = 0.f;
  #pragma unroll
  for (int i = 0; i < 2; i++)
    #pragma unroll
    for (int j = 0; j < 2; j++)
      #pragma unroll
      for (int r = 0; r < 16; r++) s += acc[i][j][r];
  for (int off = 32; off; off >>= 1) s += __shfl_down(s, off);
  if (l == 0) red[w] = s;
  __syncthreads();
  if (tid == 0) {
    float T = red[0] + red[1] + red[2] + red[3]
            + red[4] + red[5] + red[6] + red[7];
    atomicAdd(&tot[b], T);
  }

  // ---- sq[b][c]: diagonal contributions ----
  if ((rh * 2 + tr) == tc && lk == ((l >> 2) & 1)) {
    const int c = l & 31;
    const int r = (c >> 3) * 4 + (c & 3);   // reg holding row==col
    #pragma unroll
    for (int i = 0; i < 2; i++)
      atomicAdd(&sq[b * N_ + tc * 64 + i * 32 + c], acc[i][i][r]);
  }
  #undef LOADH
  #undef WRITEH
  #undef MFMA2
}

// Sum 4 partials inline, reconstruct L2, 5-kernel exp with quadrant signs.
// 512 blocks (8 row-chunks x 64 batches, 2 blocks/CU), float4 loads.
__global__ __launch_bounds__(512, 4) void k_exp(
    const float* __restrict__ partial, const float* __restrict__ tot,
    const float* __restrict__ sq, float* __restrict__ out) {
  __shared__ float sqs[N_];
  __shared__ float red[8];
  __shared__ float bws;
  const int rc = blockIdx.x;           // 0..7: 32-row chunk
  const int b  = blockIdx.y;
  const int t  = threadIdx.x;          // 512
  const int cg = t & 63;               // col group (x4)
  const int rg = t >> 6;               // 0..7: 4-row group

  if (t < N_) sqs[t] = sq[b * N_ + t];
  __syncthreads();
  if (t < N_) {
    float v = sqs[t];
    for (int off = 32; off; off >>= 1) v += __shfl_down(v, off);
    if ((t & 63) == 0) red[t >> 6] = v;
  }
  __syncthreads();
  if (t == 0) {
    float ssq = red[0] + red[1] + red[2] + red[3];
    float SL2 = 2.f * (float)N_ * ssq - 2.f * tot[b];
    bws = SL2 / (float)(N_ * N_ - N_) * 0.25f;  // / kernel_mul^(num//2)
  }
  __syncthreads();

  const float bwv = bws;
  float nb[5];
  #pragma unroll
  for (int k = 0; k < 5; k++)
    nb[k] = -1.4426950408889634f / (bwv * (float)(1 << k));

  const int c4 = cg * 4;
  const float4 sqc = *(const float4*)&sqs[c4];
  const float sgn = ((rc < 4) == (cg < 32)) ? 1.f : -1.f;  // quadrant sign
  const float* p0 = partial + (size_t)b * TILE_;

  float accv = 0.f;
  #pragma unroll
  for (int r = 0; r < 4; r++) {
    const int row = rc * 32 + rg * 4 + r;
    const float4 g0 = *(const float4*)&p0[row * N_ + c4];
    const float4 g1 = *(const float4*)&p0[(size_t)1 * B_ * TILE_ + row * N_ + c4];
    const float4 g2 = *(const float4*)&p0[(size_t)2 * B_ * TILE_ + row * N_ + c4];
    const float4 g3 = *(const float4*)&p0[(size_t)3 * B_ * TILE_ + row * N_ + c4];
    const float sr = sqs[row];
    float4 L2;
    L2.x = sr + sqc.x - 2.f * (g0.x + g1.x + g2.x + g3.x);
    L2.y = sr + sqc.y - 2.f * (g0.y + g1.y + g2.y + g3.y);
    L2.z = sr + sqc.z - 2.f * (g0.z + g1.z + g2.z + g3.z);
    L2.w = sr + sqc.w - 2.f * (g0.w + g1.w + g2.w + g3.w);
    #pragma unroll
    for (int k = 0; k < 5; k++) {
      accv += exp2f(L2.x * nb[k]) + exp2f(L2.y * nb[k])
            + exp2f(L2.z * nb[k]) + exp2f(L2.w * nb[k]);
    }
  }
  accv *= sgn;
  for (int off = 32; off; off >>= 1) accv += __shfl_down(accv, off);
  __syncthreads();  // red[] reuse safe (t==0 consumed it before bws barrier)
  if ((t & 63) == 0) red[t >> 6] = accv;
  __syncthreads();
  if (t == 0) {
    float s2 = red[0] + red[1] + red[2] + red[3]
             + red[4] + red[5] + red[6] + red[7];
    atomicAdd(out, s2 * (1.0f / (64.f * 16384.f)));  // / (B * S*S)
  }
}

extern "C" void kernel_launch(void* const* d_in, const int* in_sizes, int n_in,
                              void* d_out, int out_size, void* d_ws, size_t ws_size,
                              hipStream_t stream) {
  const float* src = (const float*)d_in[0];
  const float* tgt = (const float*)d_in[1];
  const size_t partial_bytes = (size_t)KC_ * B_ * TILE_ * sizeof(float);  // 67 MB
  float* partial = (float*)d_ws;
  float* tot     = (float*)((char*)d_ws + partial_bytes);         // 64 floats
  float* sq      = tot + B_;                                      // 64*256 floats
  hipMemsetAsync(tot, 0, (B_ + B_ * N_) * sizeof(float), stream);
  hipMemsetAsync(d_out, 0, sizeof(float), stream);
  k_gram<<<dim3(KC_ * 2, B_), 512, 0, stream>>>(src, tgt, partial, tot, sq);
  k_exp<<<dim3(8, B_), 512, 0, stream>>>(partial, tot, sq, (float*)d_out);
}